// Round 6
// baseline (1588.072 us; speedup 1.0000x reference)
//
#include <hip/hip_runtime.h>
#include <math.h>

// Problem dims (fixed by setup_inputs)
#define MTOK 4096
#define DDIM 1024
#define NEXP 16
#define PSLOT 1024
#define NPDIM 16384   // NEXP*PSLOT
#define HDIM 1365
#define HPAD 1376     // HDIM rounded to multiple of 32 (K-tile), 16B-aligned rows
#define KSPL 4        // split-K factor for the final combine GEMM

typedef unsigned short u16;  // raw bf16
typedef __attribute__((ext_vector_type(8))) short short8;     // MFMA A/B frag (8 bf16)
typedef __attribute__((ext_vector_type(8))) unsigned short ushort8;
typedef __attribute__((ext_vector_type(2))) unsigned int uint32x2;
typedef __attribute__((ext_vector_type(4))) unsigned int uint32x4;
typedef __attribute__((ext_vector_type(4))) float f32x4;      // MFMA C/D frag

template<bool Bc, typename T, typename F> struct cond_t { using type = T; };
template<typename T, typename F> struct cond_t<false, T, F> { using type = F; };

__device__ __forceinline__ float b2f(u16 v) {
    union { unsigned int u; float f; } x;
    x.u = ((unsigned int)v) << 16;
    return x.f;
}
// integer RTNE (scalar path: epilogue/softmax)
__device__ __forceinline__ u16 f2b(float f) {
    union { float f; unsigned int u; } x;
    x.f = f;
    unsigned int r = x.u + 0x7FFFu + ((x.u >> 16) & 1u);
    return (u16)(r >> 16);
}
// HW packed RTNE convert: 2 f32 -> u32 of 2 bf16 (lo, hi).
__device__ __forceinline__ unsigned int cvtpk(float lo, float hi) {
    unsigned int r;
    asm("v_cvt_pk_bf16_f32 %0, %1, %2" : "=v"(r) : "v"(lo), "v"(hi));
    return r;
}
__device__ __forceinline__ void stv(float* p, long long i, float v) { p[i] = v; }
__device__ __forceinline__ void stv(u16*  p, long long i, float v) { p[i] = f2b(v); }

// Fused counted-wait + barrier. "memory" clobber = compiler fence: no LDS or
// global access migrates across; the asm supplies the waits __syncthreads
// would have (lgkmcnt(0) for ds_write->barrier->ds_read ordering; counted
// vmcnt for DMA completion) WITHOUT draining the register prefetch.
#define BAR_LGKM()  asm volatile("s_waitcnt lgkmcnt(0)\ns_barrier" ::: "memory")
#define BAR_VM(N)   asm volatile("s_waitcnt vmcnt(" #N ") lgkmcnt(0)\ns_barrier" ::: "memory")

// ---------------------------------------------------------------------------
// MFMA GEMM: C[M,N] = A' * B (+bias)(relu)(*rowsc), fp32 accumulate.
//   AMODE 0: A is bf16 [M,K] row-major -> global_load_lds (dims must be exact)
//   AMODE 2: A is bf16 [K,M] row-major (logical A^T), scaled by S[k][col&1023]
//   B is [K,N] row-major (fp32 or bf16), transpose-staged to Bs[n][k].
//   BCHK: per-tile wave-uniform bounds test; edge tiles use always-issue
//         clamped loads + select (static VMEM inst count -> vmcnt(4) safe).
// 256x128 tile, BK=32, 512 threads / 8 waves (4x2), 4x4 16x16x32 frags/wave.
// R6 pipeline: raw-barrier with counted waits (T4-lite) + depth-2 register
// prefetch for reg-staged paths.
//   AMODE 2: A/B raw loads 2 K-steps ahead (ping-pong reg sets, x2-unrolled
//     loop -> static indexing). Scale loads depth-1, issued FIRST each step so
//     the compiler's auto vmcnt wait at WRITEA (in-order retire) keeps the
//     new set in flight. Barrier = lgkmcnt(0) only: all vmem deps are
//     register-dataflow, compiler emits counted vmcnt(N) itself.
//   AMODE 0: DMA depth-1 (2 bufs); barrier = vmcnt(4)+lgkmcnt(0). 4 <= B
//     prefetch inst count always (bf16: 4 unmergeable u32; fp32: 4-8), and
//     vmcnt retires in order => <=4 outstanding implies both DMAs landed.
//     sched_barrier(0) pins DMA-before-B issue order. Tails use vmcnt(0).
// Same one-barrier-per-K-step placement as the verified R3-R5 template.
// ---------------------------------------------------------------------------
template<int AMODE, typename TA, typename TB, typename TC,
         bool BIASF, bool RELUF, bool ROWSC, bool BCHK>
__global__ __launch_bounds__(512) void mgemm(
    const TA* __restrict__ A, long long sA, int lda,
    const TB* __restrict__ B, long long sB, int ldb,
    TC* __restrict__ C, long long sC, int ldc,
    const float* __restrict__ S,
    const float* __restrict__ bias, long long sBias,
    const float* __restrict__ rowsc,
    int M, int N, int NZ, int K, int Kb, int Nb)
{
    constexpr int AS = (AMODE == 0) ? 32 : 40;  // As row stride (elements)
    constexpr int BS = 40;                      // Bs row stride (elements)
    __shared__ u16 As[2][256 * AS];
    __shared__ u16 Bs[2][128 * BS];

    const int bz = blockIdx.z;
    A += (long long)bz * sA;
    B += (long long)bz * sB;
    C += (long long)bz * sC;
    const float* biasp = BIASF ? (bias + (long long)bz * sBias) : nullptr;

    // Bijective XCD-chunked swizzle (m204): works for any nwg.
    const int gx = gridDim.x;
    const int nwg = gx * gridDim.y;
    int wg = blockIdx.x + gx * blockIdx.y;
    {
        const int q = nwg >> 3, r = nwg & 7, xc = wg & 7, ix = wg >> 3;
        wg = (xc < r ? xc * (q + 1) : r + xc * q) + ix;
    }
    const int m0 = (wg / gx) * 256;
    const int n0 = (wg % gx) * 128;

    const int tid  = threadIdx.x;
    const int lane = tid & 63;
    const int wv   = tid >> 6;       // wave 0..7
    const int wm   = wv & 3;         // wave row (4x2)
    const int wn   = wv >> 2;        // wave col
    const int quad = lane >> 4;
    const int l16  = lane & 15;

    // A staging coords (AMODE2): 2 adjacent cols x 8 k per thread
    const int cla  = 2 * (tid & 127);   // 128 col-pairs = 256 cols
    const int k8a  = tid >> 7;          // 0..3, 8 k each
    // B staging coords: 2 adjacent cols x 4 k per thread
    const int clb  = 2 * (tid & 63);    // 64 col-pairs = 128 cols
    const int kqb  = tid >> 6;          // 0..7, 4 k each
    const int ngb  = n0 + clb;

    // swizzled LDS element offsets (kel = element offset within the row)
    auto aoff = [&](int row, int k8) {
        int o = row * AS + k8 * 8;
        if constexpr (AMODE != 0) o ^= ((row >> 3) & 3) << 3;
        return o;
    };
    auto boff = [&](int row, int kel) {
        return (row * BS + kel) ^ (((row >> 3) & 3) << 3);
    };

    f32x4 acc[4][4];
#pragma unroll
    for (int i = 0; i < 4; ++i)
#pragma unroll
        for (int j = 0; j < 4; ++j) acc[i][j] = (f32x4){0.f, 0.f, 0.f, 0.f};

    using BRAW = typename cond_t<sizeof(TB) == 2, unsigned int[4], float[8]>::type;

    // ---- phase helpers -----------------------------------------------------
    auto LOADA0 = [&](int k0, int buf) {   // AMODE 0: direct-to-LDS DMA
#pragma unroll
        for (int q = 0; q < 2; ++q) {
            const u16* gp = A + (long long)(m0 + wv * 32 + q * 16 + (lane >> 2)) * lda
                              + k0 + (lane & 3) * 8;
            u16* lp = &As[buf][(wv * 32 + q * 16) * 32];  // wave-uniform
            __builtin_amdgcn_global_load_lds(
                (const __attribute__((address_space(1))) unsigned int*)gp,
                (__attribute__((address_space(3))) unsigned int*)lp, 16, 0, 0);
        }
    };
    auto LOADA2 = [&](int k0, unsigned int (&araw)[8]) {  // AMODE 2: raw u32
#pragma unroll
        for (int i = 0; i < 8; ++i) {
            const long long kg = k0 + k8a * 8 + i;
            araw[i] = *(const unsigned int*)((const u16*)A + kg * lda + (m0 + cla));
        }
    };
    auto LOADS = [&](int k0, float2 (&sr)[8]) {           // AMODE 2: scales
#pragma unroll
        for (int i = 0; i < 8; ++i)
            sr[i] = *(const float2*)&S[(long long)(k0 + k8a * 8 + i) * 1024
                                       + ((m0 + cla) & 1023)];
    };
    auto WRITEA = [&](int buf, unsigned int (&araw)[8], float2 (&sr)[8]) {
        uint32x4 wa, wb;
#pragma unroll
        for (int j = 0; j < 4; ++j) {   // pair k = 2j, 2j+1 (same col)
            const unsigned int r0 = araw[2 * j], r1 = araw[2 * j + 1];
            wa[j] = cvtpk(b2f((u16)(r0 & 0xFFFFu)) * sr[2 * j].x,
                          b2f((u16)(r1 & 0xFFFFu)) * sr[2 * j + 1].x);
            wb[j] = cvtpk(b2f((u16)(r0 >> 16)) * sr[2 * j].y,
                          b2f((u16)(r1 >> 16)) * sr[2 * j + 1].y);
        }
        *(uint32x4*)&As[buf][aoff(cla, k8a)]     = wa;
        *(uint32x4*)&As[buf][aoff(cla + 1, k8a)] = wb;
    };
    auto LOADB = [&](int k0, BRAW& braw) {
        if constexpr (sizeof(TB) == 2) {
            // bf16 (BCHK=false): raw u32 copy; 4 insts at 32KB stride (no merge)
#pragma unroll
            for (int i = 0; i < 4; ++i) {
                const int kg = k0 + kqb * 4 + i;
                braw[i] = *(const unsigned int*)((const u16*)B + (long long)kg * ldb + ngb);
            }
        } else {
            bool full = true;
            if constexpr (BCHK) full = (k0 + 32 <= Kb) && (n0 + 128 <= Nb);
            if (full) {
#pragma unroll
                for (int i = 0; i < 4; ++i) {
                    const int kg = k0 + kqb * 4 + i;
                    const float* bp = (const float*)B + (long long)kg * ldb + ngb;
                    braw[2 * i]     = bp[0];
                    braw[2 * i + 1] = bp[1];
                }
            } else {
                // edge: ALWAYS-ISSUE clamped loads + select (static inst count)
#pragma unroll
                for (int i = 0; i < 4; ++i) {
                    const int kg  = k0 + kqb * 4 + i;
                    const int kgc = kg < Kb ? kg : Kb - 1;
                    const int c0  = ngb     < Nb ? ngb     : Nb - 1;
                    const int c1  = ngb + 1 < Nb ? ngb + 1 : Nb - 1;
                    const float* bp = (const float*)B + (long long)kgc * ldb;
                    const float v0 = bp[c0];
                    const float v1 = bp[c1];
                    braw[2 * i]     = (kg < Kb && ngb     < Nb) ? v0 : 0.f;
                    braw[2 * i + 1] = (kg < Kb && ngb + 1 < Nb) ? v1 : 0.f;
                }
            }
        }
    };
    auto WRITEB = [&](int buf, BRAW& braw) {
        uint32x2 wa, wb;
        if constexpr (sizeof(TB) == 2) {
            // repack (col-pairs per k) -> (k-pairs per col)
            wa[0] = (braw[0] & 0xFFFFu) | (braw[1] << 16);
            wa[1] = (braw[2] & 0xFFFFu) | (braw[3] << 16);
            wb[0] = (braw[0] >> 16) | (braw[1] & 0xFFFF0000u);
            wb[1] = (braw[2] >> 16) | (braw[3] & 0xFFFF0000u);
        } else {
            wa[0] = cvtpk(braw[0], braw[2]);
            wa[1] = cvtpk(braw[4], braw[6]);
            wb[0] = cvtpk(braw[1], braw[3]);
            wb[1] = cvtpk(braw[5], braw[7]);
        }
        *(uint32x2*)&Bs[buf][boff(clb, kqb * 4)]     = wa;
        *(uint32x2*)&Bs[buf][boff(clb + 1, kqb * 4)] = wb;
    };
    auto MM = [&](int buf) {
        short8 bfr[4];
#pragma unroll
        for (int ni = 0; ni < 4; ++ni)
            bfr[ni] = *(const short8*)&Bs[buf][boff(wn * 64 + ni * 16 + l16, quad * 8)];
#pragma unroll
        for (int mi = 0; mi < 4; ++mi) {
            short8 a = *(const short8*)&As[buf][aoff(wm * 64 + mi * 16 + l16, quad)];
#pragma unroll
            for (int ni = 0; ni < 4; ++ni)
                acc[mi][ni] = __builtin_amdgcn_mfma_f32_16x16x32_bf16(a, bfr[ni], acc[mi][ni], 0, 0, 0);
        }
    };

    // ---- pipelined K loop (depth-2 reg prefetch, counted-wait barriers) ----
    const int nt = K >> 5;  // all K here are multiples of 32; nt >= 32
    unsigned int a0[8], a1[8];
    BRAW b0, b1;
    float2 sr[8];

    auto STEP = [&](int t, unsigned int (&ha)[8], BRAW& hb,
                    unsigned int (&na)[8], BRAW& nb) {
        const int nxt = (t + 1) & 1;
        const bool pf1 = (t + 1 < nt), pf2 = (t + 2 < nt);
        if constexpr (AMODE == 0) {
            if (pf1) LOADA0((t + 1) * 32, nxt);          // DMA tile t+1
            __builtin_amdgcn_sched_barrier(0);           // pin DMA before B loads
            if (pf2) LOADB((t + 2) * 32, nb);            // B tile t+2 -> regs
            MM(t & 1);
            if (pf1) WRITEB(nxt, hb);                    // auto vmcnt: hold only
            if (pf2) { BAR_VM(4); } else { BAR_VM(0); }  // DMA landed; nb in flight
        } else {
            if (pf1) LOADS((t + 1) * 32, sr);            // scales first (oldest)
            if (pf2) { LOADA2((t + 2) * 32, na); LOADB((t + 2) * 32, nb); }
            MM(t & 1);
            if (pf1) { WRITEA(nxt, ha, sr); WRITEB(nxt, hb); }  // auto counted vmcnt
            BAR_LGKM();                                  // ds_writes visible
        }
    };

    // prologue
    if constexpr (AMODE == 0) {
        LOADA0(0, 0);
        __builtin_amdgcn_sched_barrier(0);
        LOADB(0, b0);
        WRITEB(0, b0);        // auto wait drains b0 loads (and the older DMA)
        LOADB(32, b1);        // tile 1 B in flight across the barrier
        BAR_LGKM();
    } else {
        LOADA2(0, a0); LOADB(0, b0); LOADS(0, sr);
        WRITEA(0, a0, sr); WRITEB(0, b0);
        LOADA2(32, a1); LOADB(32, b1);   // tile 1 in flight across the barrier
        BAR_LGKM();
    }
    for (int t = 0; t < nt; t += 2) {
        STEP(t, a1, b1, a0, b0);                 // hold = tile t+1, new = t+2
        if (t + 1 < nt) STEP(t + 1, a0, b0, a1, b1);
    }

    // ---------------- epilogue ----------------
#pragma unroll
    for (int mi = 0; mi < 4; ++mi) {
#pragma unroll
        for (int r = 0; r < 4; ++r) {
            const int rg = m0 + wm * 64 + mi * 16 + quad * 4 + r;
            if (rg >= M) continue;
            const float rs = ROWSC ? rowsc[rg] : 1.f;
#pragma unroll
            for (int ni = 0; ni < 4; ++ni) {
                const int cg = n0 + wn * 64 + ni * 16 + l16;
                if (cg < N) {
                    float v = acc[mi][ni][r];
                    if (BIASF) v += biasp[cg];
                    if (RELUF) v = fmaxf(v, 0.f);
                    if (ROWSC) v *= rs;
                    stv(C, (long long)rg * ldc + cg, v);
                } else if (cg < NZ) {
                    stv(C, (long long)rg * ldc + cg, 0.f);  // zero K-pad cols
                }
            }
        }
    }
}

// ---------------------------------------------------------------------------
// fp32 -> bf16 bulk convert (8 elems/thread, exact grids)
// ---------------------------------------------------------------------------
__global__ __launch_bounds__(256) void cvt_k(
    const float* __restrict__ src, u16* __restrict__ dst, long long n)
{
    const long long i = ((long long)blockIdx.x * 256 + threadIdx.x) * 8;
    if (i >= n) return;
    const float4 a = *(const float4*)&src[i];
    const float4 b = *(const float4*)&src[i + 4];
    uint32x4 v;
    v[0] = cvtpk(a.x, a.y);
    v[1] = cvtpk(a.z, a.w);
    v[2] = cvtpk(b.x, b.y);
    v[3] = cvtpk(b.z, b.w);
    *(uint32x4*)&dst[i] = v;
}

// ---------------------------------------------------------------------------
// Softmax pass over bf16 logits: L[m,:] -> E = exp(L - rowmax) in place (bf16);
//   rsc[m] = 1/sum(E);  rsd[m,p] = 1/sum_n E[m, n*P + p]   (fp32 outputs)
// ---------------------------------------------------------------------------
__global__ __launch_bounds__(256) void softmax_k(
    u16* __restrict__ L, float* __restrict__ rsd, float* __restrict__ rsc)
{
    const int m = blockIdx.x;
    u16* row = L + (long long)m * NPDIM;
    const int tid = threadIdx.x;
    __shared__ float red[256];

    float mx = -1e30f;
    for (int i = tid * 8; i < NPDIM; i += 2048) {
        const ushort8 v = *(const ushort8*)&row[i];
#pragma unroll
        for (int j = 0; j < 8; ++j) mx = fmaxf(mx, b2f(v[j]));
    }
    red[tid] = mx;
    __syncthreads();
    for (int s = 128; s > 0; s >>= 1) {
        if (tid < s) red[tid] = fmaxf(red[tid], red[tid + s]);
        __syncthreads();
    }
    const float mxAll = red[0];
    __syncthreads();

    float sum = 0.f;
    for (int i = tid * 8; i < NPDIM; i += 2048) {
        const ushort8 v = *(const ushort8*)&row[i];
        ushort8 e;
#pragma unroll
        for (int j = 0; j < 8; ++j) {
            const float ef = __expf(b2f(v[j]) - mxAll);
            const u16 eb = f2b(ef);
            e[j] = eb;
            sum += b2f(eb);
        }
        *(ushort8*)&row[i] = e;
    }
    red[tid] = sum;
    __syncthreads();
    for (int s = 128; s > 0; s >>= 1) {
        if (tid < s) red[tid] += red[tid + s];
        __syncthreads();
    }
    if (tid == 0) rsc[m] = 1.f / red[0];
    __syncthreads();

    {   // rsd: 4 consecutive p per thread (256*4 = 1024)
        const int p0 = tid * 4;
        float s0 = 0.f, s1 = 0.f, s2 = 0.f, s3 = 0.f;
#pragma unroll
        for (int n = 0; n < NEXP; ++n) {
            const ushort4 v = *(const ushort4*)&row[n * PSLOT + p0];
            s0 += b2f(v.x); s1 += b2f(v.y); s2 += b2f(v.z); s3 += b2f(v.w);
        }
        const float4 r = {1.f / s0, 1.f / s1, 1.f / s2, 1.f / s3};
        *(float4*)&rsd[(long long)m * PSLOT + p0] = r;
    }
}

// ---------------------------------------------------------------------------
// Sum the KSPL split-K partials -> Y.  Grid sized exactly: MTOK*PSLOT/(4*256).
// ---------------------------------------------------------------------------
__global__ __launch_bounds__(256) void reduce_k(
    const float* __restrict__ Yp, float* __restrict__ Y)
{
    const long long S = (long long)MTOK * PSLOT;
    const long long i = ((long long)blockIdx.x * 256 + threadIdx.x) * 4;
    f32x4 r = *(const f32x4*)&Yp[i];
#pragma unroll
    for (int z = 1; z < KSPL; ++z) r += *(const f32x4*)&Yp[(long long)z * S + i];
    *(f32x4*)&Y[i] = r;
}

extern "C" void kernel_launch(void* const* d_in, const int* in_sizes, int n_in,
                              void* d_out, int out_size, void* d_ws, size_t ws_size,
                              hipStream_t stream)
{
    const float* x   = (const float*)d_in[0];  // [4096,1024]
    const float* phi = (const float*)d_in[1];  // [1024,16,1024]
    const float* W1  = (const float*)d_in[2];  // [16,1024,1365]
    const float* b1  = (const float*)d_in[3];  // [16,1365]
    const float* W2  = (const float*)d_in[4];  // [16,1365,1024]
    const float* b2  = (const float*)d_in[5];  // [16,1024]
    float* Y = (float*)d_out;                  // [4096,1024] fp32

    // Workspace (~253 MB). Aliases (lifetime-disjoint):
    //   phib (32 MB) overlays Ys   [phib: pre -> step1; Ys: step5 -> step6]
    //   xb   ( 8 MB) overlays Hb   [xb:   pre -> step3; Hb: step4 -> step5]
    //   Yp   (64 MB) overlays rsd+Xs+Hb [all dead by step 6]
    char* w = (char*)d_ws;
    u16*   L    = (u16*)w;   w += (size_t)MTOK * NPDIM * 2;          // 128 MB (logits -> E)
    u16*   Ys   = (u16*)w;   w += (size_t)NEXP * PSLOT * PSLOT * 2;  // 32 MB
    float* rsc  = (float*)w; w += (size_t)MTOK * 4;                  // 16 KB
    float* Yp   = (float*)w;                                         // 64 MB alias
    float* rsd  = (float*)w; w += (size_t)MTOK * PSLOT * 4;          // 16 MB
    u16*   Xs   = (u16*)w;   w += (size_t)NEXP * PSLOT * DDIM * 2;   // 32 MB
    u16*   Hb   = (u16*)w;   w += (size_t)NEXP * PSLOT * HPAD * 2;   // 45.1 MB
    u16*   phib = Ys;                                                // bf16 phi
    u16*   xb   = Hb;                                                // bf16 x

    // 0) one-shot bf16 conversions of x and phi
    cvt_k<<<dim3((MTOK * DDIM) / (8 * 256)), 256, 0, stream>>>(x, xb, (long long)MTOK * DDIM);
    cvt_k<<<dim3((DDIM * NPDIM) / (8 * 256)), 256, 0, stream>>>(phi, phib, (long long)DDIM * NPDIM);

    // 1) L = xb @ phib   [4096,16384], K=1024  (AMODE 0 DMA + raw-u32 B)
    mgemm<0, u16, u16, u16, false, false, false, false>
        <<<dim3(NPDIM / 128, MTOK / 256, 1), 512, 0, stream>>>(
        xb, 0, DDIM,  phib, 0, NPDIM,  L, 0, NPDIM,
        nullptr, nullptr, 0, nullptr,
        MTOK, NPDIM, NPDIM, DDIM, DDIM, NPDIM);

    // 2) E = exp(L - max) in place; rsd, rsc
    softmax_k<<<dim3(MTOK), 256, 0, stream>>>(L, rsd, rsc);

    // 3) Xs[np,d] = sum_m (E*rsd)[m,np] * x[m,d]   (A^T staging + scale, K=4096)
    mgemm<2, u16, u16, u16, false, false, false, false>
        <<<dim3(DDIM / 128, NPDIM / 256, 1), 512, 0, stream>>>(
        L, 0, NPDIM,  xb, 0, DDIM,  Xs, 0, DDIM,
        rsd, nullptr, 0, nullptr,
        NPDIM, DDIM, DDIM, MTOK, MTOK, DDIM);

    // 4) H = relu(Xs @ W1 + b1) per expert  [1024,1365]->[1024,1376], K=1024
    mgemm<0, u16, float, u16, true, true, false, true>
        <<<dim3((HPAD + 127) / 128, PSLOT / 256, NEXP), 512, 0, stream>>>(
        Xs, (long long)PSLOT * DDIM, DDIM,
        W1, (long long)DDIM * HDIM, HDIM,
        Hb, (long long)PSLOT * HPAD, HPAD,
        nullptr, b1, HDIM, nullptr,
        PSLOT, HDIM, HPAD, DDIM, DDIM, HDIM);

    // 5) Ys = H @ W2 + b2 per expert  [1024,1024], K=1376 (pad zeros both sides)
    mgemm<0, u16, float, u16, true, false, false, true>
        <<<dim3(PSLOT / 128, PSLOT / 256, NEXP), 512, 0, stream>>>(
        Hb, (long long)PSLOT * HPAD, HPAD,
        W2, (long long)HDIM * PSLOT, PSLOT,
        Ys, (long long)PSLOT * PSLOT, PSLOT,
        nullptr, b2, PSLOT, nullptr,
        PSLOT, PSLOT, PSLOT, HPAD, HDIM, PSLOT);

    // 6) Y[m,o] = rsc[m] * sum_np E[m,np] * Ys[np,o]   [4096,1024], K=16384
    //    Split-K x4: 512 blocks (2/CU) so TLP hides staging latency.
    mgemm<0, u16, u16, float, false, false, true, false>
        <<<dim3(PSLOT / 128, MTOK / 256, KSPL), 512, 0, stream>>>(
        L, (long long)(NPDIM / KSPL), NPDIM,
        Ys, (long long)(NPDIM / KSPL) * PSLOT, PSLOT,
        Yp, (long long)MTOK * PSLOT, PSLOT,
        nullptr, nullptr, 0, rsc,
        MTOK, PSLOT, PSLOT, NPDIM / KSPL, NPDIM / KSPL, PSLOT);

    // 7) Y = sum_z Yp[z]
    reduce_k<<<dim3((MTOK * PSLOT) / (4 * 256)), 256, 0, stream>>>(Yp, Y);
}

// Round 7
// 1170.727 us; speedup vs baseline: 1.3565x; 1.3565x over previous
//
#include <hip/hip_runtime.h>
#include <math.h>

// Problem dims (fixed by setup_inputs)
#define MTOK 4096
#define DDIM 1024
#define NEXP 16
#define PSLOT 1024
#define NPDIM 16384   // NEXP*PSLOT
#define HDIM 1365
#define HPAD 1376     // HDIM rounded to multiple of 32 (K-tile), 16B-aligned rows
#define KSPL 4        // split-K factor for the final combine GEMM

typedef unsigned short u16;  // raw bf16
typedef __attribute__((ext_vector_type(8))) short short8;     // MFMA A/B frag (8 bf16)
typedef __attribute__((ext_vector_type(8))) unsigned short ushort8;
typedef __attribute__((ext_vector_type(2))) unsigned int uint32x2;
typedef __attribute__((ext_vector_type(4))) unsigned int uint32x4;
typedef __attribute__((ext_vector_type(4))) float f32x4;      // MFMA C/D frag

template<bool Bc, typename T, typename F> struct cond_t { using type = T; };
template<typename T, typename F> struct cond_t<false, T, F> { using type = F; };

__device__ __forceinline__ float b2f(u16 v) {
    union { unsigned int u; float f; } x;
    x.u = ((unsigned int)v) << 16;
    return x.f;
}
// integer RTNE (scalar path: epilogue/softmax)
__device__ __forceinline__ u16 f2b(float f) {
    union { float f; unsigned int u; } x;
    x.f = f;
    unsigned int r = x.u + 0x7FFFu + ((x.u >> 16) & 1u);
    return (u16)(r >> 16);
}
// HW packed RTNE convert: 2 f32 -> u32 of 2 bf16 (lo, hi).
__device__ __forceinline__ unsigned int cvtpk(float lo, float hi) {
    unsigned int r;
    asm("v_cvt_pk_bf16_f32 %0, %1, %2" : "=v"(r) : "v"(lo), "v"(hi));
    return r;
}
__device__ __forceinline__ void stv(float* p, long long i, float v) { p[i] = v; }
__device__ __forceinline__ void stv(u16*  p, long long i, float v) { p[i] = f2b(v); }

// ---------------------------------------------------------------------------
// MFMA GEMM: C[M,N] = A' * B (+bias)(relu)(*rowsc), fp32 accumulate.
//   AMODE 0: A is bf16 [M,K] row-major -> global_load_lds DMA
//   AMODE 2: A is bf16 [K,M] row-major (logical A^T), scaled by S[k][col&1023]
//   BMODE 0: B passed as B^T [N,K] row-major bf16 (k-contiguous rows) ->
//            global_load_lds DMA, linear Bs [n][32] (both sides linear, rule 21)
//   BMODE 1: B is [K,N] row-major (fp32 or bf16), reg transpose-staged to
//            swizzled Bs[n][k] (R4 XOR swizzle).
//   BCHK: per-tile wave-uniform bounds test vs (Kb, Nb); edge tiles scalar.
// 256x128 tile, BK=32, 512 threads / 8 waves (4x2), 4x4 16x16x32 frags/wave.
// Verified R5 2-phase pipeline: issue t+1 loads -> MFMA(t) -> convert+ds_write
// -> ONE __syncthreads per K-step (its vmcnt/lgkm drain is the needed wait).
// R7: pre-transposed B (steps 1/3) makes the B side pure DMA; Bs stride 40->32
// drops LDS so AMODE0+BMODE0=48K, AMODE0+BMODE1=52K -> 3 blocks/CU.
// ---------------------------------------------------------------------------
template<int AMODE, int BMODE, typename TA, typename TB, typename TC,
         bool BIASF, bool RELUF, bool ROWSC, bool BCHK>
__global__ __launch_bounds__(512) void mgemm(
    const TA* __restrict__ A, long long sA, int lda,
    const TB* __restrict__ B, long long sB, int ldb,
    TC* __restrict__ C, long long sC, int ldc,
    const float* __restrict__ S,
    const float* __restrict__ bias, long long sBias,
    const float* __restrict__ rowsc,
    int M, int N, int NZ, int K, int Kb, int Nb)
{
    constexpr int AS = (AMODE == 0) ? 32 : 40;  // As row stride (elements)
    constexpr int BS = (BMODE == 0) ? 32 : 40;  // Bs row stride (elements)
    __shared__ u16 As[2][256 * AS];
    __shared__ u16 Bs[2][128 * BS];

    const int bz = blockIdx.z;
    A += (long long)bz * sA;
    B += (long long)bz * sB;
    C += (long long)bz * sC;
    const float* biasp = BIASF ? (bias + (long long)bz * sBias) : nullptr;

    // Bijective XCD-chunked swizzle (m204): works for any nwg.
    const int gx = gridDim.x;
    const int nwg = gx * gridDim.y;
    int wg = blockIdx.x + gx * blockIdx.y;
    {
        const int q = nwg >> 3, r = nwg & 7, xc = wg & 7, ix = wg >> 3;
        wg = (xc < r ? xc * (q + 1) : r + xc * q) + ix;
    }
    const int m0 = (wg / gx) * 256;
    const int n0 = (wg % gx) * 128;

    const int tid  = threadIdx.x;
    const int lane = tid & 63;
    const int wv   = tid >> 6;       // wave 0..7
    const int wm   = wv & 3;         // wave row (4x2)
    const int wn   = wv >> 2;        // wave col
    const int quad = lane >> 4;
    const int l16  = lane & 15;

    // A staging coords (AMODE2): 2 adjacent cols x 8 k per thread
    const int cla  = 2 * (tid & 127);   // 128 col-pairs = 256 cols
    const int k8a  = tid >> 7;          // 0..3, 8 k each
    // B staging coords (BMODE1): 2 adjacent cols x 4 k per thread
    const int clb  = 2 * (tid & 63);    // 64 col-pairs = 128 cols
    const int kqb  = tid >> 6;          // 0..7, 4 k each
    const int ngb  = n0 + clb;

    // LDS element offsets (kel = element offset within the row)
    auto aoff = [&](int row, int k8) {
        int o = row * AS + k8 * 8;
        if constexpr (AMODE != 0) o ^= ((row >> 3) & 3) << 3;
        return o;
    };
    auto boff = [&](int row, int kel) {
        int o = row * BS + kel;
        if constexpr (BMODE != 0) o ^= ((row >> 3) & 3) << 3;
        return o;
    };

    f32x4 acc[4][4];
#pragma unroll
    for (int i = 0; i < 4; ++i)
#pragma unroll
        for (int j = 0; j < 4; ++j) acc[i][j] = (f32x4){0.f, 0.f, 0.f, 0.f};

    using BRAW = typename cond_t<sizeof(TB) == 2, unsigned int[4], float[8]>::type;

    // ---- phase helpers -----------------------------------------------------
    auto LOADA0 = [&](int k0, int buf) {   // AMODE 0: direct-to-LDS DMA
#pragma unroll
        for (int q = 0; q < 2; ++q) {
            const u16* gp = A + (long long)(m0 + wv * 32 + q * 16 + (lane >> 2)) * lda
                              + k0 + (lane & 3) * 8;
            u16* lp = &As[buf][(wv * 32 + q * 16) * 32];  // wave-uniform
            __builtin_amdgcn_global_load_lds(
                (const __attribute__((address_space(1))) unsigned int*)gp,
                (__attribute__((address_space(3))) unsigned int*)lp, 16, 0, 0);
        }
    };
    auto LOADA2 = [&](int k0, unsigned int (&araw)[8], float2 (&sr)[8]) {
#pragma unroll
        for (int i = 0; i < 8; ++i) {
            const long long kg = k0 + k8a * 8 + i;
            araw[i] = *(const unsigned int*)((const u16*)A + kg * lda + (m0 + cla));
            sr[i]   = *(const float2*)&S[kg * 1024 + ((m0 + cla) & 1023)];
        }
    };
    auto WRITEA = [&](int buf, unsigned int (&araw)[8], float2 (&sr)[8]) {
        uint32x4 wa, wb;
#pragma unroll
        for (int j = 0; j < 4; ++j) {   // pair k = 2j, 2j+1 (same col)
            const unsigned int r0 = araw[2 * j], r1 = araw[2 * j + 1];
            wa[j] = cvtpk(b2f((u16)(r0 & 0xFFFFu)) * sr[2 * j].x,
                          b2f((u16)(r1 & 0xFFFFu)) * sr[2 * j + 1].x);
            wb[j] = cvtpk(b2f((u16)(r0 >> 16)) * sr[2 * j].y,
                          b2f((u16)(r1 >> 16)) * sr[2 * j + 1].y);
        }
        *(uint32x4*)&As[buf][aoff(cla, k8a)]     = wa;
        *(uint32x4*)&As[buf][aoff(cla + 1, k8a)] = wb;
    };
    auto LOADB0 = [&](int k0, int buf) {   // BMODE 0: B^T [N,K] row DMA
        const u16* gp = (const u16*)B + (long long)(n0 + wv * 16 + (lane >> 2)) * ldb
                          + k0 + (lane & 3) * 8;
        u16* lp = &Bs[buf][(wv * 16) * 32];  // wave-uniform
        __builtin_amdgcn_global_load_lds(
            (const __attribute__((address_space(1))) unsigned int*)gp,
            (__attribute__((address_space(3))) unsigned int*)lp, 16, 0, 0);
    };
    auto LOADB = [&](int k0, BRAW& braw) {  // BMODE 1 (R5 path)
        if constexpr (sizeof(TB) == 2) {
#pragma unroll
            for (int i = 0; i < 4; ++i) {
                const int kg = k0 + kqb * 4 + i;
                braw[i] = *(const unsigned int*)((const u16*)B + (long long)kg * ldb + ngb);
            }
        } else {
            bool full = true;
            if constexpr (BCHK) full = (k0 + 32 <= Kb) && (n0 + 128 <= Nb);
            if (full) {
#pragma unroll
                for (int i = 0; i < 4; ++i) {
                    const int kg = k0 + kqb * 4 + i;
                    const float* bp = (const float*)B + (long long)kg * ldb + ngb;
                    braw[2 * i]     = bp[0];
                    braw[2 * i + 1] = bp[1];
                }
            } else {
#pragma unroll
                for (int i = 0; i < 4; ++i) {
                    const int kg = k0 + kqb * 4 + i;
                    float v0 = 0.f, v1 = 0.f;
                    if (kg < Kb) {
                        if (ngb < Nb)     v0 = ((const float*)B)[(long long)kg * ldb + ngb];
                        if (ngb + 1 < Nb) v1 = ((const float*)B)[(long long)kg * ldb + ngb + 1];
                    }
                    braw[2 * i]     = v0;
                    braw[2 * i + 1] = v1;
                }
            }
        }
    };
    auto WRITEB = [&](int buf, BRAW& braw) {
        uint32x2 wa, wb;
        if constexpr (sizeof(TB) == 2) {
            // repack (col-pairs per k) -> (k-pairs per col)
            wa[0] = (braw[0] & 0xFFFFu) | (braw[1] << 16);
            wa[1] = (braw[2] & 0xFFFFu) | (braw[3] << 16);
            wb[0] = (braw[0] >> 16) | (braw[1] & 0xFFFF0000u);
            wb[1] = (braw[2] >> 16) | (braw[3] & 0xFFFF0000u);
        } else {
            wa[0] = cvtpk(braw[0], braw[2]);
            wa[1] = cvtpk(braw[4], braw[6]);
            wb[0] = cvtpk(braw[1], braw[3]);
            wb[1] = cvtpk(braw[5], braw[7]);
        }
        *(uint32x2*)&Bs[buf][boff(clb, kqb * 4)]     = wa;
        *(uint32x2*)&Bs[buf][boff(clb + 1, kqb * 4)] = wb;
    };
    auto MM = [&](int buf) {
        short8 bfr[4];
#pragma unroll
        for (int ni = 0; ni < 4; ++ni)
            bfr[ni] = *(const short8*)&Bs[buf][boff(wn * 64 + ni * 16 + l16, quad * 8)];
#pragma unroll
        for (int mi = 0; mi < 4; ++mi) {
            short8 a = *(const short8*)&As[buf][aoff(wm * 64 + mi * 16 + l16, quad)];
#pragma unroll
            for (int ni = 0; ni < 4; ++ni)
                acc[mi][ni] = __builtin_amdgcn_mfma_f32_16x16x32_bf16(a, bfr[ni], acc[mi][ni], 0, 0, 0);
        }
    };

    // ---- pipelined K loop (verified R5 2-phase structure) ------------------
    const int nt = K >> 5;  // all K here are multiples of 32
    unsigned int a0[8];
    float2 sr[8];
    BRAW braw;
    {   // prologue: stage tile 0 into buf 0
        if constexpr (AMODE == 0) LOADA0(0, 0);
        else                      LOADA2(0, a0, sr);
        if constexpr (BMODE == 0) LOADB0(0, 0);
        else                      LOADB(0, braw);
        if constexpr (AMODE != 0) WRITEA(0, a0, sr);
        if constexpr (BMODE != 0) WRITEB(0, braw);
        __syncthreads();  // drains DMA (vmcnt) + ds_writes (lgkmcnt)
    }
    for (int t = 0; t < nt; ++t) {
        const int cur = t & 1, nxt = cur ^ 1;
        const bool pf = (t + 1 < nt);
        if (pf) {                       // issue next-tile loads FIRST
            if constexpr (AMODE == 0) LOADA0((t + 1) * 32, nxt);
            else                      LOADA2((t + 1) * 32, a0, sr);
            if constexpr (BMODE == 0) LOADB0((t + 1) * 32, nxt);
            else                      LOADB((t + 1) * 32, braw);
        }
        MM(cur);                        // compute under the loads' latency
        if (pf) {                       // convert + LDS-write after compute
            if constexpr (AMODE != 0) WRITEA(nxt, a0, sr);
            if constexpr (BMODE != 0) WRITEB(nxt, braw);
        }
        __syncthreads();                // one barrier per K-step
    }

    // ---------------- epilogue ----------------
#pragma unroll
    for (int mi = 0; mi < 4; ++mi) {
#pragma unroll
        for (int r = 0; r < 4; ++r) {
            const int rg = m0 + wm * 64 + mi * 16 + quad * 4 + r;
            if (rg >= M) continue;
            const float rs = ROWSC ? rowsc[rg] : 1.f;
#pragma unroll
            for (int ni = 0; ni < 4; ++ni) {
                const int cg = n0 + wn * 64 + ni * 16 + l16;
                if (cg < N) {
                    float v = acc[mi][ni][r];
                    if (BIASF) v += biasp[cg];
                    if (RELUF) v = fmaxf(v, 0.f);
                    if (ROWSC) v *= rs;
                    stv(C, (long long)rg * ldc + cg, v);
                } else if (cg < NZ) {
                    stv(C, (long long)rg * ldc + cg, 0.f);  // zero K-pad cols
                }
            }
        }
    }
}

// ---------------------------------------------------------------------------
// fp32 -> bf16 bulk convert (8 elems/thread, exact grids)
// ---------------------------------------------------------------------------
__global__ __launch_bounds__(256) void cvt_k(
    const float* __restrict__ src, u16* __restrict__ dst, long long n)
{
    const long long i = ((long long)blockIdx.x * 256 + threadIdx.x) * 8;
    if (i >= n) return;
    const float4 a = *(const float4*)&src[i];
    const float4 b = *(const float4*)&src[i + 4];
    uint32x4 v;
    v[0] = cvtpk(a.x, a.y);
    v[1] = cvtpk(a.z, a.w);
    v[2] = cvtpk(b.x, b.y);
    v[3] = cvtpk(b.z, b.w);
    *(uint32x4*)&dst[i] = v;
}

// ---------------------------------------------------------------------------
// fp32 [R,C] -> bf16 transpose [C,R]; 32x32 LDS tiles (+1 pad), 256 threads.
// R, C multiples of 32. Read float4 coalesced; write ushort4 (8B) coalesced.
// ---------------------------------------------------------------------------
__global__ __launch_bounds__(256) void tcvt_k(
    const float* __restrict__ src, u16* __restrict__ dst, int R, int C)
{
    __shared__ float t[32][33];
    const int c0 = blockIdx.x * 32, r0 = blockIdx.y * 32;
    const int tr = threadIdx.x >> 3;          // 0..31
    const int tc = (threadIdx.x & 7) * 4;     // 0,4,...,28
    const float4 v = *(const float4*)&src[(long long)(r0 + tr) * C + c0 + tc];
    t[tr][tc]     = v.x;
    t[tr][tc + 1] = v.y;
    t[tr][tc + 2] = v.z;
    t[tr][tc + 3] = v.w;
    __syncthreads();
    uint32x2 o;
    o[0] = cvtpk(t[tc][tr],     t[tc + 1][tr]);
    o[1] = cvtpk(t[tc + 2][tr], t[tc + 3][tr]);
    *(uint32x2*)&dst[(long long)(c0 + tr) * R + r0 + tc] = o;
}

// ---------------------------------------------------------------------------
// Softmax pass over bf16 logits: L[m,:] -> E = exp(L - rowmax) in place (bf16);
//   rsc[m] = 1/sum(E);  rsd[m,p] = 1/sum_n E[m, n*P + p]   (fp32 outputs)
// ---------------------------------------------------------------------------
__global__ __launch_bounds__(256) void softmax_k(
    u16* __restrict__ L, float* __restrict__ rsd, float* __restrict__ rsc)
{
    const int m = blockIdx.x;
    u16* row = L + (long long)m * NPDIM;
    const int tid = threadIdx.x;
    __shared__ float red[256];

    float mx = -1e30f;
    for (int i = tid * 8; i < NPDIM; i += 2048) {
        const ushort8 v = *(const ushort8*)&row[i];
#pragma unroll
        for (int j = 0; j < 8; ++j) mx = fmaxf(mx, b2f(v[j]));
    }
    red[tid] = mx;
    __syncthreads();
    for (int s = 128; s > 0; s >>= 1) {
        if (tid < s) red[tid] = fmaxf(red[tid], red[tid + s]);
        __syncthreads();
    }
    const float mxAll = red[0];
    __syncthreads();

    float sum = 0.f;
    for (int i = tid * 8; i < NPDIM; i += 2048) {
        const ushort8 v = *(const ushort8*)&row[i];
        ushort8 e;
#pragma unroll
        for (int j = 0; j < 8; ++j) {
            const float ef = __expf(b2f(v[j]) - mxAll);
            const u16 eb = f2b(ef);
            e[j] = eb;
            sum += b2f(eb);
        }
        *(ushort8*)&row[i] = e;
    }
    red[tid] = sum;
    __syncthreads();
    for (int s = 128; s > 0; s >>= 1) {
        if (tid < s) red[tid] += red[tid + s];
        __syncthreads();
    }
    if (tid == 0) rsc[m] = 1.f / red[0];
    __syncthreads();

    {   // rsd: 4 consecutive p per thread (256*4 = 1024)
        const int p0 = tid * 4;
        float s0 = 0.f, s1 = 0.f, s2 = 0.f, s3 = 0.f;
#pragma unroll
        for (int n = 0; n < NEXP; ++n) {
            const ushort4 v = *(const ushort4*)&row[n * PSLOT + p0];
            s0 += b2f(v.x); s1 += b2f(v.y); s2 += b2f(v.z); s3 += b2f(v.w);
        }
        const float4 r = {1.f / s0, 1.f / s1, 1.f / s2, 1.f / s3};
        *(float4*)&rsd[(long long)m * PSLOT + p0] = r;
    }
}

// ---------------------------------------------------------------------------
// Sum the KSPL split-K partials -> Y.  Grid sized exactly: MTOK*PSLOT/(4*256).
// ---------------------------------------------------------------------------
__global__ __launch_bounds__(256) void reduce_k(
    const float* __restrict__ Yp, float* __restrict__ Y)
{
    const long long S = (long long)MTOK * PSLOT;
    const long long i = ((long long)blockIdx.x * 256 + threadIdx.x) * 4;
    f32x4 r = *(const f32x4*)&Yp[i];
#pragma unroll
    for (int z = 1; z < KSPL; ++z) r += *(const f32x4*)&Yp[(long long)z * S + i];
    *(f32x4*)&Y[i] = r;
}

extern "C" void kernel_launch(void* const* d_in, const int* in_sizes, int n_in,
                              void* d_out, int out_size, void* d_ws, size_t ws_size,
                              hipStream_t stream)
{
    const float* x   = (const float*)d_in[0];  // [4096,1024]
    const float* phi = (const float*)d_in[1];  // [1024,16,1024]
    const float* W1  = (const float*)d_in[2];  // [16,1024,1365]
    const float* b1  = (const float*)d_in[3];  // [16,1365]
    const float* W2  = (const float*)d_in[4];  // [16,1365,1024]
    const float* b2  = (const float*)d_in[5];  // [16,1024]
    float* Y = (float*)d_out;                  // [4096,1024] fp32

    // Workspace (~253 MB). Aliases (lifetime-disjoint):
    //   phibT (32 MB) overlays Ys      [phibT: pre -> step1; Ys: step5 -> step6]
    //   xb+xbT (16 MB) overlay Hb      [xb/xbT: pre -> step3; Hb: step4 -> step5]
    //   Yp   (64 MB) overlays rsd+Xs+Hb [all dead by step 6]
    char* w = (char*)d_ws;
    u16*   L     = (u16*)w;   w += (size_t)MTOK * NPDIM * 2;          // 128 MB (logits -> E)
    u16*   Ys    = (u16*)w;   w += (size_t)NEXP * PSLOT * PSLOT * 2;  // 32 MB
    float* rsc   = (float*)w; w += (size_t)MTOK * 4;                  // 16 KB
    float* Yp    = (float*)w;                                         // 64 MB alias
    float* rsd   = (float*)w; w += (size_t)MTOK * PSLOT * 4;          // 16 MB
    u16*   Xs    = (u16*)w;   w += (size_t)NEXP * PSLOT * DDIM * 2;   // 32 MB
    u16*   Hb    = (u16*)w;   w += (size_t)NEXP * PSLOT * HPAD * 2;   // 45.1 MB
    u16*   phibT = Ys;                                                // phi^T bf16 [16384,1024]
    u16*   xb    = Hb;                                                // x bf16 [4096,1024]
    u16*   xbT   = Hb + (size_t)MTOK * DDIM;                          // x^T bf16 [1024,4096]

    // 0) one-shot bf16 conversions / transposes
    cvt_k<<<dim3((MTOK * DDIM) / (8 * 256)), 256, 0, stream>>>(x, xb, (long long)MTOK * DDIM);
    tcvt_k<<<dim3(DDIM / 32, MTOK / 32), 256, 0, stream>>>(x, xbT, MTOK, DDIM);
    tcvt_k<<<dim3(NPDIM / 32, DDIM / 32), 256, 0, stream>>>(phi, phibT, DDIM, NPDIM);

    // 1) L = xb @ phi   [4096,16384], K=1024  (A DMA + B^T DMA: pure-DMA body)
    mgemm<0, 0, u16, u16, u16, false, false, false, false>
        <<<dim3(NPDIM / 128, MTOK / 256, 1), 512, 0, stream>>>(
        xb, 0, DDIM,  phibT, 0, DDIM,  L, 0, NPDIM,
        nullptr, nullptr, 0, nullptr,
        MTOK, NPDIM, NPDIM, DDIM, DDIM, NPDIM);

    // 2) E = exp(L - max) in place; rsd, rsc
    softmax_k<<<dim3(MTOK), 256, 0, stream>>>(L, rsd, rsc);

    // 3) Xs[np,d] = sum_m (E*rsd)[m,np] * x[m,d]  (A^T reg-stage + scale; B^T DMA)
    mgemm<2, 0, u16, u16, u16, false, false, false, false>
        <<<dim3(DDIM / 128, NPDIM / 256, 1), 512, 0, stream>>>(
        L, 0, NPDIM,  xbT, 0, MTOK,  Xs, 0, DDIM,
        rsd, nullptr, 0, nullptr,
        NPDIM, DDIM, DDIM, MTOK, MTOK, DDIM);

    // 4) H = relu(Xs @ W1 + b1) per expert  [1024,1365]->[1024,1376], K=1024
    mgemm<0, 1, u16, float, u16, true, true, false, true>
        <<<dim3((HPAD + 127) / 128, PSLOT / 256, NEXP), 512, 0, stream>>>(
        Xs, (long long)PSLOT * DDIM, DDIM,
        W1, (long long)DDIM * HDIM, HDIM,
        Hb, (long long)PSLOT * HPAD, HPAD,
        nullptr, b1, HDIM, nullptr,
        PSLOT, HDIM, HPAD, DDIM, DDIM, HDIM);

    // 5) Ys = H @ W2 + b2 per expert  [1024,1024], K=1376 (pad zeros both sides)
    mgemm<0, 1, u16, float, u16, true, false, false, true>
        <<<dim3(PSLOT / 128, PSLOT / 256, NEXP), 512, 0, stream>>>(
        Hb, (long long)PSLOT * HPAD, HPAD,
        W2, (long long)HDIM * PSLOT, PSLOT,
        Ys, (long long)PSLOT * PSLOT, PSLOT,
        nullptr, b2, PSLOT, nullptr,
        PSLOT, PSLOT, PSLOT, HPAD, HDIM, PSLOT);

    // 6) Y[m,o] = rsc[m] * sum_np E[m,np] * Ys[np,o]   [4096,1024], K=16384
    //    Split-K x4: 512 blocks so TLP hides staging latency.
    mgemm<0, 1, u16, u16, float, false, false, true, false>
        <<<dim3(PSLOT / 128, MTOK / 256, KSPL), 512, 0, stream>>>(
        L, (long long)(NPDIM / KSPL), NPDIM,
        Ys, (long long)(NPDIM / KSPL) * PSLOT, PSLOT,
        Yp, (long long)MTOK * PSLOT, PSLOT,
        nullptr, nullptr, 0, rsc,
        MTOK, PSLOT, PSLOT, NPDIM / KSPL, NPDIM / KSPL, PSLOT);

    // 7) Y = sum_z Yp[z]
    reduce_k<<<dim3((MTOK * PSLOT) / (4 * 256)), 256, 0, stream>>>(Yp, Y);
}

// Round 8
// 1149.792 us; speedup vs baseline: 1.3812x; 1.0182x over previous
//
#include <hip/hip_runtime.h>
#include <math.h>

// Problem dims (fixed by setup_inputs)
#define MTOK 4096
#define DDIM 1024
#define NEXP 16
#define PSLOT 1024
#define NPDIM 16384   // NEXP*PSLOT
#define HDIM 1365
#define HPAD 1376     // HDIM rounded to multiple of 32 (K-tile), 16B-aligned rows
#define KSPL 4        // split-K factor for the final combine GEMM

typedef unsigned short u16;  // raw bf16
typedef __attribute__((ext_vector_type(8))) short short8;     // MFMA A/B frag (8 bf16)
typedef __attribute__((ext_vector_type(8))) unsigned short ushort8;
typedef __attribute__((ext_vector_type(2))) unsigned int uint32x2;
typedef __attribute__((ext_vector_type(4))) unsigned int uint32x4;
typedef __attribute__((ext_vector_type(4))) float f32x4;      // MFMA C/D frag

template<bool Bc, typename T, typename F> struct cond_t { using type = T; };
template<typename T, typename F> struct cond_t<false, T, F> { using type = F; };

struct b16raw  { unsigned int v[4]; };  // bf16 B staging regs (2col x 4k)
struct f32raw  { float v[8]; };         // fp32 B staging regs (2col x 4k)
struct f32raw4 { f32x4 v[2]; };         // fp32 B staging regs (4col x 2k, aligned)

__device__ __forceinline__ float b2f(u16 v) {
    union { unsigned int u; float f; } x;
    x.u = ((unsigned int)v) << 16;
    return x.f;
}
// integer RTNE (scalar path: epilogue/softmax)
__device__ __forceinline__ u16 f2b(float f) {
    union { float f; unsigned int u; } x;
    x.f = f;
    unsigned int r = x.u + 0x7FFFu + ((x.u >> 16) & 1u);
    return (u16)(r >> 16);
}
// HW packed RTNE convert: 2 f32 -> u32 of 2 bf16 (lo, hi).
__device__ __forceinline__ unsigned int cvtpk(float lo, float hi) {
    unsigned int r;
    asm("v_cvt_pk_bf16_f32 %0, %1, %2" : "=v"(r) : "v"(lo), "v"(hi));
    return r;
}
__device__ __forceinline__ void stv(float* p, long long i, float v) { p[i] = v; }
__device__ __forceinline__ void stv(u16*  p, long long i, float v) { p[i] = f2b(v); }

// ---------------------------------------------------------------------------
// MFMA GEMM: C[M,N] = A' * B (+bias)(relu)(*rowsc), fp32 accumulate.
//   AMODE 0: A is bf16 [M,K] row-major -> global_load_lds DMA
//   AMODE 2: A is bf16 [K,M] row-major (logical A^T), scaled by S[k][col&1023]
//            R8: 4col x 4k patch -> 4 uint2 + 4 float4 loads (was 8+8),
//            scale loads fully coalesced (1 KB/wave-inst).
//   BMODE 0: B passed as B^T [N,K] row-major bf16 -> global_load_lds DMA
//   BMODE 1: B is [K,N] row-major (fp32 or bf16), reg transpose-staged to
//            swizzled Bs. BAL4: fp32 with ldb%4==0 -> 4col x 2k float4 path.
//   BCHK: per-tile block-uniform bounds test vs (Kb, Nb); edge tiles scalar.
// 256x128 tile, BK=32, 512 threads / 8 waves (4x2), 4x4 16x16x32 frags/wave.
// Verified R5 2-phase pipeline: issue t+1 loads -> MFMA(t) -> convert+ds_write
// -> ONE __syncthreads per K-step. (R6's hand-counted vmcnt/depth-2 regressed;
// per-CU cycle model shows the loop is at ~86% of multi-pipe issue floor, so
// R8 reduces instruction counts, not latency.)
// ---------------------------------------------------------------------------
template<int AMODE, int BMODE, typename TA, typename TB, typename TC,
         bool BIASF, bool RELUF, bool ROWSC, bool BCHK, bool BAL4>
__global__ __launch_bounds__(512) void mgemm(
    const TA* __restrict__ A, long long sA, int lda,
    const TB* __restrict__ B, long long sB, int ldb,
    TC* __restrict__ C, long long sC, int ldc,
    const float* __restrict__ S,
    const float* __restrict__ bias, long long sBias,
    const float* __restrict__ rowsc,
    int M, int N, int NZ, int K, int Kb, int Nb)
{
    constexpr int AS = (AMODE == 0) ? 32 : 40;  // As row stride (elements)
    constexpr int BS = (BMODE == 0) ? 32 : 40;  // Bs row stride (elements)
    __shared__ u16 As[2][256 * AS];
    __shared__ u16 Bs[2][128 * BS];

    const int bz = blockIdx.z;
    A += (long long)bz * sA;
    B += (long long)bz * sB;
    C += (long long)bz * sC;
    const float* biasp = BIASF ? (bias + (long long)bz * sBias) : nullptr;

    // Bijective XCD-chunked swizzle (m204): works for any nwg.
    const int gx = gridDim.x;
    const int nwg = gx * gridDim.y;
    int wg = blockIdx.x + gx * blockIdx.y;
    {
        const int q = nwg >> 3, r = nwg & 7, xc = wg & 7, ix = wg >> 3;
        wg = (xc < r ? xc * (q + 1) : r + xc * q) + ix;
    }
    const int m0 = (wg / gx) * 256;
    const int n0 = (wg % gx) * 128;

    const int tid  = threadIdx.x;
    const int lane = tid & 63;
    const int wv   = tid >> 6;       // wave 0..7
    const int wm   = wv & 3;         // wave row (4x2)
    const int wn   = wv >> 2;        // wave col
    const int quad = lane >> 4;
    const int l16  = lane & 15;

    // A staging coords (AMODE2): 4 adjacent cols x 4 k per thread
    const int cg4  = 4 * (tid & 63);    // 64 col-quads = 256 cols
    const int kg4  = (tid >> 6) * 4;    // 8 k-quads = 32 k
    // B staging coords (BMODE1, generic): 2 adjacent cols x 4 k per thread
    const int clb  = 2 * (tid & 63);    // 64 col-pairs = 128 cols
    const int kqb  = tid >> 6;          // 0..7, 4 k each
    const int ngb  = n0 + clb;
    // B staging coords (BMODE1, BAL4): 4 adjacent cols x 2 k per thread
    const int cb4  = 4 * (tid & 31);    // 32 col-quads = 128 cols
    const int kb2  = (tid >> 5) * 2;    // 16 k-pairs = 32 k

    // LDS element offsets (kel = element offset within the row)
    auto aoff = [&](int row, int kel) {
        int o = row * AS + kel;
        if constexpr (AMODE != 0) o ^= ((row >> 3) & 3) << 3;
        return o;
    };
    auto boff = [&](int row, int kel) {
        int o = row * BS + kel;
        if constexpr (BMODE != 0) o ^= ((row >> 3) & 3) << 3;
        return o;
    };

    f32x4 acc[4][4];
#pragma unroll
    for (int i = 0; i < 4; ++i)
#pragma unroll
        for (int j = 0; j < 4; ++j) acc[i][j] = (f32x4){0.f, 0.f, 0.f, 0.f};

    using BRAW = typename cond_t<sizeof(TB) == 2, b16raw,
                   typename cond_t<BAL4, f32raw4, f32raw>::type>::type;

    // ---- phase helpers -----------------------------------------------------
    auto LOADA0 = [&](int k0, int buf) {   // AMODE 0: direct-to-LDS DMA
#pragma unroll
        for (int q = 0; q < 2; ++q) {
            const u16* gp = A + (long long)(m0 + wv * 32 + q * 16 + (lane >> 2)) * lda
                              + k0 + (lane & 3) * 8;
            u16* lp = &As[buf][(wv * 32 + q * 16) * 32];  // wave-uniform
            __builtin_amdgcn_global_load_lds(
                (const __attribute__((address_space(1))) unsigned int*)gp,
                (__attribute__((address_space(3))) unsigned int*)lp, 16, 0, 0);
        }
    };
    auto LOADA2 = [&](int k0, uint2 (&araw)[4], f32x4 (&sr)[4]) {
#pragma unroll
        for (int j = 0; j < 4; ++j) {
            const long long kg = k0 + kg4 + j;
            araw[j] = *(const uint2*)((const u16*)A + kg * lda + (m0 + cg4));
            sr[j]   = *(const f32x4*)&S[kg * 1024 + ((m0 + cg4) & 1023)];
        }
    };
    auto WRITEA = [&](int buf, uint2 (&araw)[4], f32x4 (&sr)[4]) {
        // value(col r, k j) = b2f(bits(araw[j], col r)) * sr[j][r]
#pragma unroll
        for (int r = 0; r < 4; ++r) {
            float e[4];
#pragma unroll
            for (int j = 0; j < 4; ++j) {
                const unsigned int h = (r & 2) ? araw[j].y : araw[j].x;
                const u16 b = (r & 1) ? (u16)(h >> 16) : (u16)(h & 0xFFFFu);
                e[j] = b2f(b) * sr[j][r];
            }
            uint32x2 wp;
            wp[0] = cvtpk(e[0], e[1]);
            wp[1] = cvtpk(e[2], e[3]);
            *(uint32x2*)&As[buf][aoff(cg4 + r, kg4)] = wp;
        }
    };
    auto LOADB0 = [&](int k0, int buf) {   // BMODE 0: B^T [N,K] row DMA
        const u16* gp = (const u16*)B + (long long)(n0 + wv * 16 + (lane >> 2)) * ldb
                          + k0 + (lane & 3) * 8;
        u16* lp = &Bs[buf][(wv * 16) * 32];  // wave-uniform
        __builtin_amdgcn_global_load_lds(
            (const __attribute__((address_space(1))) unsigned int*)gp,
            (__attribute__((address_space(3))) unsigned int*)lp, 16, 0, 0);
    };
    auto LOADB = [&](int k0, BRAW& braw) {  // BMODE 1
        if constexpr (sizeof(TB) == 2) {
#pragma unroll
            for (int i = 0; i < 4; ++i) {
                const int kg = k0 + kqb * 4 + i;
                braw.v[i] = *(const unsigned int*)((const u16*)B + (long long)kg * ldb + ngb);
            }
        } else if constexpr (BAL4) {
            // 4col x 2k float4 (ldb % 4 == 0); edge rows zero-filled/partial
            bool full = true;
            if constexpr (BCHK) full = (k0 + 32 <= Kb) && (n0 + 128 <= Nb);
            if (full) {
#pragma unroll
                for (int j = 0; j < 2; ++j) {
                    const int kg = k0 + kb2 + j;
                    braw.v[j] = *(const f32x4*)((const float*)B + (long long)kg * ldb + n0 + cb4);
                }
            } else {
#pragma unroll
                for (int j = 0; j < 2; ++j) {
                    const int kg = k0 + kb2 + j;
                    f32x4 f = (f32x4){0.f, 0.f, 0.f, 0.f};
                    if (kg < Kb) {
                        if (n0 + 128 <= Nb) {
                            f = *(const f32x4*)((const float*)B + (long long)kg * ldb + n0 + cb4);
                        } else {
#pragma unroll
                            for (int r = 0; r < 4; ++r)
                                if (n0 + cb4 + r < Nb)
                                    f[r] = ((const float*)B)[(long long)kg * ldb + n0 + cb4 + r];
                        }
                    }
                    braw.v[j] = f;
                }
            }
        } else {
            bool full = true;
            if constexpr (BCHK) full = (k0 + 32 <= Kb) && (n0 + 128 <= Nb);
            if (full) {
#pragma unroll
                for (int i = 0; i < 4; ++i) {
                    const int kg = k0 + kqb * 4 + i;
                    const float* bp = (const float*)B + (long long)kg * ldb + ngb;
                    braw.v[2 * i]     = bp[0];   // ldb may be odd -> scalar loads
                    braw.v[2 * i + 1] = bp[1];
                }
            } else {
#pragma unroll
                for (int i = 0; i < 4; ++i) {
                    const int kg = k0 + kqb * 4 + i;
                    float v0 = 0.f, v1 = 0.f;
                    if (kg < Kb) {
                        if (ngb < Nb)     v0 = ((const float*)B)[(long long)kg * ldb + ngb];
                        if (ngb + 1 < Nb) v1 = ((const float*)B)[(long long)kg * ldb + ngb + 1];
                    }
                    braw.v[2 * i]     = v0;
                    braw.v[2 * i + 1] = v1;
                }
            }
        }
    };
    auto WRITEB = [&](int buf, BRAW& braw) {
        if constexpr (sizeof(TB) == 2) {
            uint32x2 wa, wb;
            // repack (col-pairs per k) -> (k-pairs per col)
            wa[0] = (braw.v[0] & 0xFFFFu) | (braw.v[1] << 16);
            wa[1] = (braw.v[2] & 0xFFFFu) | (braw.v[3] << 16);
            wb[0] = (braw.v[0] >> 16) | (braw.v[1] & 0xFFFF0000u);
            wb[1] = (braw.v[2] >> 16) | (braw.v[3] & 0xFFFF0000u);
            *(uint32x2*)&Bs[buf][boff(clb, kqb * 4)]     = wa;
            *(uint32x2*)&Bs[buf][boff(clb + 1, kqb * 4)] = wb;
        } else if constexpr (BAL4) {
#pragma unroll
            for (int r = 0; r < 4; ++r)
                *(unsigned int*)&Bs[buf][boff(cb4 + r, kb2)] =
                    cvtpk(braw.v[0][r], braw.v[1][r]);
        } else {
            uint32x2 wa, wb;
            wa[0] = cvtpk(braw.v[0], braw.v[2]);
            wa[1] = cvtpk(braw.v[4], braw.v[6]);
            wb[0] = cvtpk(braw.v[1], braw.v[3]);
            wb[1] = cvtpk(braw.v[5], braw.v[7]);
            *(uint32x2*)&Bs[buf][boff(clb, kqb * 4)]     = wa;
            *(uint32x2*)&Bs[buf][boff(clb + 1, kqb * 4)] = wb;
        }
    };
    auto MM = [&](int buf) {
        short8 bfr[4];
#pragma unroll
        for (int ni = 0; ni < 4; ++ni)
            bfr[ni] = *(const short8*)&Bs[buf][boff(wn * 64 + ni * 16 + l16, quad * 8)];
#pragma unroll
        for (int mi = 0; mi < 4; ++mi) {
            short8 a = *(const short8*)&As[buf][aoff(wm * 64 + mi * 16 + l16, quad * 8)];
#pragma unroll
            for (int ni = 0; ni < 4; ++ni)
                acc[mi][ni] = __builtin_amdgcn_mfma_f32_16x16x32_bf16(a, bfr[ni], acc[mi][ni], 0, 0, 0);
        }
    };

    // ---- pipelined K loop (verified R5 2-phase structure) ------------------
    const int nt = K >> 5;  // all K here are multiples of 32
    uint2 a0[4];
    f32x4 sr[4];
    BRAW braw;
    {   // prologue: stage tile 0 into buf 0
        if constexpr (AMODE == 0) LOADA0(0, 0);
        else                      LOADA2(0, a0, sr);
        if constexpr (BMODE == 0) LOADB0(0, 0);
        else                      LOADB(0, braw);
        if constexpr (AMODE != 0) WRITEA(0, a0, sr);
        if constexpr (BMODE != 0) WRITEB(0, braw);
        __syncthreads();  // drains DMA (vmcnt) + ds_writes (lgkmcnt)
    }
    for (int t = 0; t < nt; ++t) {
        const int cur = t & 1, nxt = cur ^ 1;
        const bool pf = (t + 1 < nt);
        if (pf) {                       // issue next-tile loads FIRST
            if constexpr (AMODE == 0) LOADA0((t + 1) * 32, nxt);
            else                      LOADA2((t + 1) * 32, a0, sr);
            if constexpr (BMODE == 0) LOADB0((t + 1) * 32, nxt);
            else                      LOADB((t + 1) * 32, braw);
        }
        MM(cur);                        // compute under the loads' latency
        if (pf) {                       // convert + LDS-write after compute
            if constexpr (AMODE != 0) WRITEA(nxt, a0, sr);
            if constexpr (BMODE != 0) WRITEB(nxt, braw);
        }
        __syncthreads();                // one barrier per K-step
    }

    // ---------------- epilogue ----------------
#pragma unroll
    for (int mi = 0; mi < 4; ++mi) {
#pragma unroll
        for (int r = 0; r < 4; ++r) {
            const int rg = m0 + wm * 64 + mi * 16 + quad * 4 + r;
            if (rg >= M) continue;
            const float rs = ROWSC ? rowsc[rg] : 1.f;
#pragma unroll
            for (int ni = 0; ni < 4; ++ni) {
                const int cg = n0 + wn * 64 + ni * 16 + l16;
                if (cg < N) {
                    float v = acc[mi][ni][r];
                    if (BIASF) v += biasp[cg];
                    if (RELUF) v = fmaxf(v, 0.f);
                    if (ROWSC) v *= rs;
                    stv(C, (long long)rg * ldc + cg, v);
                } else if (cg < NZ) {
                    stv(C, (long long)rg * ldc + cg, 0.f);  // zero K-pad cols
                }
            }
        }
    }
}

// ---------------------------------------------------------------------------
// fp32 [R,C] -> bf16 row-major copy AND bf16 transpose [C,R], one pass.
// 32x32 LDS tiles (+1 pad), 256 threads. R, C multiples of 32.
// ---------------------------------------------------------------------------
__global__ __launch_bounds__(256) void xcvt_k(
    const float* __restrict__ src, u16* __restrict__ dst_rm,
    u16* __restrict__ dst_tr, int R, int C)
{
    __shared__ float t[32][33];
    const int c0 = blockIdx.x * 32, r0 = blockIdx.y * 32;
    const int tr = threadIdx.x >> 3;          // 0..31
    const int tc = (threadIdx.x & 7) * 4;     // 0,4,...,28
    const float4 v = *(const float4*)&src[(long long)(r0 + tr) * C + c0 + tc];
    t[tr][tc]     = v.x;
    t[tr][tc + 1] = v.y;
    t[tr][tc + 2] = v.z;
    t[tr][tc + 3] = v.w;
    uint32x2 o1;
    o1[0] = cvtpk(v.x, v.y);
    o1[1] = cvtpk(v.z, v.w);
    *(uint32x2*)&dst_rm[(long long)(r0 + tr) * C + c0 + tc] = o1;
    __syncthreads();
    uint32x2 o;
    o[0] = cvtpk(t[tc][tr],     t[tc + 1][tr]);
    o[1] = cvtpk(t[tc + 2][tr], t[tc + 3][tr]);
    *(uint32x2*)&dst_tr[(long long)(c0 + tr) * R + r0 + tc] = o;
}

// ---------------------------------------------------------------------------
// fp32 [R,C] -> bf16 transpose [C,R]; 32x32 LDS tiles (+1 pad), 256 threads.
// ---------------------------------------------------------------------------
__global__ __launch_bounds__(256) void tcvt_k(
    const float* __restrict__ src, u16* __restrict__ dst, int R, int C)
{
    __shared__ float t[32][33];
    const int c0 = blockIdx.x * 32, r0 = blockIdx.y * 32;
    const int tr = threadIdx.x >> 3;          // 0..31
    const int tc = (threadIdx.x & 7) * 4;     // 0,4,...,28
    const float4 v = *(const float4*)&src[(long long)(r0 + tr) * C + c0 + tc];
    t[tr][tc]     = v.x;
    t[tr][tc + 1] = v.y;
    t[tr][tc + 2] = v.z;
    t[tr][tc + 3] = v.w;
    __syncthreads();
    uint32x2 o;
    o[0] = cvtpk(t[tc][tr],     t[tc + 1][tr]);
    o[1] = cvtpk(t[tc + 2][tr], t[tc + 3][tr]);
    *(uint32x2*)&dst[(long long)(c0 + tr) * R + r0 + tc] = o;
}

// ---------------------------------------------------------------------------
// Softmax pass over bf16 logits: L[m,:] -> E = exp(L - rowmax) in place (bf16);
//   rsc[m] = 1/sum(E);  rsd[m,p] = 1/sum_n E[m, n*P + p]   (fp32 outputs)
// ---------------------------------------------------------------------------
__global__ __launch_bounds__(256) void softmax_k(
    u16* __restrict__ L, float* __restrict__ rsd, float* __restrict__ rsc)
{
    const int m = blockIdx.x;
    u16* row = L + (long long)m * NPDIM;
    const int tid = threadIdx.x;
    __shared__ float red[256];

    float mx = -1e30f;
    for (int i = tid * 8; i < NPDIM; i += 2048) {
        const ushort8 v = *(const ushort8*)&row[i];
#pragma unroll
        for (int j = 0; j < 8; ++j) mx = fmaxf(mx, b2f(v[j]));
    }
    red[tid] = mx;
    __syncthreads();
    for (int s = 128; s > 0; s >>= 1) {
        if (tid < s) red[tid] = fmaxf(red[tid], red[tid + s]);
        __syncthreads();
    }
    const float mxAll = red[0];
    __syncthreads();

    float sum = 0.f;
    for (int i = tid * 8; i < NPDIM; i += 2048) {
        const ushort8 v = *(const ushort8*)&row[i];
        ushort8 e;
#pragma unroll
        for (int j = 0; j < 8; ++j) {
            const float ef = __expf(b2f(v[j]) - mxAll);
            const u16 eb = f2b(ef);
            e[j] = eb;
            sum += b2f(eb);
        }
        *(ushort8*)&row[i] = e;
    }
    red[tid] = sum;
    __syncthreads();
    for (int s = 128; s > 0; s >>= 1) {
        if (tid < s) red[tid] += red[tid + s];
        __syncthreads();
    }
    if (tid == 0) rsc[m] = 1.f / red[0];
    __syncthreads();

    {   // rsd: 4 consecutive p per thread (256*4 = 1024)
        const int p0 = tid * 4;
        float s0 = 0.f, s1 = 0.f, s2 = 0.f, s3 = 0.f;
#pragma unroll
        for (int n = 0; n < NEXP; ++n) {
            const ushort4 v = *(const ushort4*)&row[n * PSLOT + p0];
            s0 += b2f(v.x); s1 += b2f(v.y); s2 += b2f(v.z); s3 += b2f(v.w);
        }
        const float4 r = {1.f / s0, 1.f / s1, 1.f / s2, 1.f / s3};
        *(float4*)&rsd[(long long)m * PSLOT + p0] = r;
    }
}

// ---------------------------------------------------------------------------
// Sum the KSPL split-K partials -> Y.  Grid sized exactly: MTOK*PSLOT/(4*256).
// ---------------------------------------------------------------------------
__global__ __launch_bounds__(256) void reduce_k(
    const float* __restrict__ Yp, float* __restrict__ Y)
{
    const long long S = (long long)MTOK * PSLOT;
    const long long i = ((long long)blockIdx.x * 256 + threadIdx.x) * 4;
    f32x4 r = *(const f32x4*)&Yp[i];
#pragma unroll
    for (int z = 1; z < KSPL; ++z) r += *(const f32x4*)&Yp[(long long)z * S + i];
    *(f32x4*)&Y[i] = r;
}

extern "C" void kernel_launch(void* const* d_in, const int* in_sizes, int n_in,
                              void* d_out, int out_size, void* d_ws, size_t ws_size,
                              hipStream_t stream)
{
    const float* x   = (const float*)d_in[0];  // [4096,1024]
    const float* phi = (const float*)d_in[1];  // [1024,16,1024]
    const float* W1  = (const float*)d_in[2];  // [16,1024,1365]
    const float* b1  = (const float*)d_in[3];  // [16,1365]
    const float* W2  = (const float*)d_in[4];  // [16,1365,1024]
    const float* b2  = (const float*)d_in[5];  // [16,1024]
    float* Y = (float*)d_out;                  // [4096,1024] fp32

    // Workspace (~253 MB). Aliases (lifetime-disjoint):
    //   phibT (32 MB) overlays Ys      [phibT: pre -> step1; Ys: step5 -> step6]
    //   xb+xbT (16 MB) overlay Hb      [xb/xbT: pre -> step3; Hb: step4 -> step5]
    //   Yp   (64 MB) overlays rsd+Xs+Hb [all dead by step 6]
    char* w = (char*)d_ws;
    u16*   L     = (u16*)w;   w += (size_t)MTOK * NPDIM * 2;          // 128 MB (logits -> E)
    u16*   Ys    = (u16*)w;   w += (size_t)NEXP * PSLOT * PSLOT * 2;  // 32 MB
    float* rsc   = (float*)w; w += (size_t)MTOK * 4;                  // 16 KB
    float* Yp    = (float*)w;                                         // 64 MB alias
    float* rsd   = (float*)w; w += (size_t)MTOK * PSLOT * 4;          // 16 MB
    u16*   Xs    = (u16*)w;   w += (size_t)NEXP * PSLOT * DDIM * 2;   // 32 MB
    u16*   Hb    = (u16*)w;   w += (size_t)NEXP * PSLOT * HPAD * 2;   // 45.1 MB
    u16*   phibT = Ys;                                                // phi^T bf16 [16384,1024]
    u16*   xb    = Hb;                                                // x bf16 [4096,1024]
    u16*   xbT   = Hb + (size_t)MTOK * DDIM;                          // x^T bf16 [1024,4096]

    // 0) one-shot bf16 conversions / transposes (xb + xbT fused, one x pass)
    xcvt_k<<<dim3(DDIM / 32, MTOK / 32), 256, 0, stream>>>(x, xb, xbT, MTOK, DDIM);
    tcvt_k<<<dim3(NPDIM / 32, DDIM / 32), 256, 0, stream>>>(phi, phibT, DDIM, NPDIM);

    // 1) L = xb @ phi   [4096,16384], K=1024  (A DMA + B^T DMA: pure-DMA body)
    mgemm<0, 0, u16, u16, u16, false, false, false, false, false>
        <<<dim3(NPDIM / 128, MTOK / 256, 1), 512, 0, stream>>>(
        xb, 0, DDIM,  phibT, 0, DDIM,  L, 0, NPDIM,
        nullptr, nullptr, 0, nullptr,
        MTOK, NPDIM, NPDIM, DDIM, DDIM, NPDIM);

    // 2) E = exp(L - max) in place; rsd, rsc
    softmax_k<<<dim3(MTOK), 256, 0, stream>>>(L, rsd, rsc);

    // 3) Xs[np,d] = sum_m (E*rsd)[m,np] * x[m,d]  (A^T 4x4-patch stage; B^T DMA)
    mgemm<2, 0, u16, u16, u16, false, false, false, false, false>
        <<<dim3(DDIM / 128, NPDIM / 256, 1), 512, 0, stream>>>(
        L, 0, NPDIM,  xbT, 0, MTOK,  Xs, 0, DDIM,
        rsd, nullptr, 0, nullptr,
        NPDIM, DDIM, DDIM, MTOK, MTOK, DDIM);

    // 4) H = relu(Xs @ W1 + b1) per expert  [1024,1365]->[1024,1376], K=1024
    //    (W1 ldb=1365 odd -> scalar B path)
    mgemm<0, 1, u16, float, u16, true, true, false, true, false>
        <<<dim3((HPAD + 127) / 128, PSLOT / 256, NEXP), 512, 0, stream>>>(
        Xs, (long long)PSLOT * DDIM, DDIM,
        W1, (long long)DDIM * HDIM, HDIM,
        Hb, (long long)PSLOT * HPAD, HPAD,
        nullptr, b1, HDIM, nullptr,
        PSLOT, HDIM, HPAD, DDIM, DDIM, HDIM);

    // 5) Ys = H @ W2 + b2 per expert  [1024,1024], K=1376 (pad zeros both sides)
    //    (W2 ldb=1024 -> BAL4 float4 B path)
    mgemm<0, 1, u16, float, u16, true, false, false, true, true>
        <<<dim3(PSLOT / 128, PSLOT / 256, NEXP), 512, 0, stream>>>(
        Hb, (long long)PSLOT * HPAD, HPAD,
        W2, (long long)HDIM * PSLOT, PSLOT,
        Ys, (long long)PSLOT * PSLOT, PSLOT,
        nullptr, b2, PSLOT, nullptr,
        PSLOT, PSLOT, PSLOT, HPAD, HDIM, PSLOT);

    // 6) Y[m,o] = rsc[m] * sum_np E[m,np] * Ys[np,o]   [4096,1024], K=16384
    //    Split-K x4: 512 blocks so TLP hides staging latency.
    mgemm<0, 1, u16, u16, float, false, false, true, false, false>
        <<<dim3(PSLOT / 128, MTOK / 256, KSPL), 512, 0, stream>>>(
        L, (long long)(NPDIM / KSPL), NPDIM,
        Ys, (long long)(NPDIM / KSPL) * PSLOT, PSLOT,
        Yp, (long long)MTOK * PSLOT, PSLOT,
        nullptr, nullptr, 0, rsc,
        MTOK, PSLOT, PSLOT, NPDIM / KSPL, NPDIM / KSPL, PSLOT);

    // 7) Y = sum_z Yp[z]
    reduce_k<<<dim3((MTOK * PSLOT) / (4 * 256)), 256, 0, stream>>>(Yp, Y);
}